// Round 6
// baseline (346.364 us; speedup 1.0000x reference)
//
#include <hip/hip_runtime.h>

typedef float f4 __attribute__((ext_vector_type(4)));

#define Hdim 64
#define Wdim 64
#define Cdim 256
#define HW (Hdim * Wdim)

// Round-5 structure + w-quarter split: 1024 blocks x 512 threads,
// 4 blocks/CU -> 8 waves/SIMD (VGPR<=64 via launch_bounds(512,8)).
// XCD decode unchanged: xcd = bid&7 owns (batch, 32-row h-band);
// working set 38 rows x 64KB = 2.4MB < 4MB per-XCD L2.
__global__ __launch_bounds__(512, 8) void selfattn_kernel(const float* __restrict__ x,
                                                          float* __restrict__ out)
{
    const int bid = blockIdx.x;
    const int k   = bid & 7;
    const int seq = bid >> 3;            // 0..127
    const int b   = k >> 1;              // batch
    const int h   = (k & 1) * 32 + (seq >> 2);
    const int wbase = (seq & 3) * 16;    // w-quarter
    const int t = threadIdx.x;           // 0..511

    __shared__ float simRed[49][16];
    __shared__ float attnBuf[49][16];
    __shared__ float redBuf[7][16];
    __shared__ float psumBuf[7][16];

    const float* xb = x + (size_t)b * (Cdim * HW);

    // ---------------- Phase A: sim[k][w] ----------------
    // thread = (w4: lane bits 0..1, cp: lane bits 2..5, dy: wave).
    // channel for iter i: c = i*16 + cp. f[j] <-> row position (w0g - 4 + j).
    {
        const int w4 = t & 3;            // w-group of 4 (16 wide)
        const int cp = (t >> 2) & 15;    // channel partition
        const int dy = t >> 6;           // wave-uniform; dy==7 idle
        const int lw0 = w4 * 4;
        const int w0g = wbase + lw0;

        if (dy < 7) {
            float sim[7][4];
            #pragma unroll
            for (int dx = 0; dx < 7; ++dx)
                #pragma unroll
                for (int p = 0; p < 4; ++p) sim[dx][p] = 0.f;

            const int row = h + dy - 3;
            if (row >= 0 && row < Hdim) {
                const bool hasL = (w0g != 0);
                const bool hasR = (w0g != 60);
                const float* xr = xb + (size_t)cp * HW + row * Wdim;
                const float* xc = xb + (size_t)cp * HW + h   * Wdim;
                for (int i = 0; i < 16; ++i) {
                    float f[12];
                    if (hasL) {
                        f4 v = *(const f4*)(xr + w0g - 4);
                        f[0]=v.x; f[1]=v.y; f[2]=v.z; f[3]=v.w;
                    } else { f[0]=0.f; f[1]=0.f; f[2]=0.f; f[3]=0.f; }
                    {
                        f4 v = *(const f4*)(xr + w0g);
                        f[4]=v.x; f[5]=v.y; f[6]=v.z; f[7]=v.w;
                    }
                    if (hasR) {
                        f4 v = *(const f4*)(xr + w0g + 4);
                        f[8]=v.x; f[9]=v.y; f[10]=v.z; f[11]=v.w;
                    } else { f[8]=0.f; f[9]=0.f; f[10]=0.f; f[11]=0.f; }
                    f4 cen = *(const f4*)(xc + w0g);
                    #pragma unroll
                    for (int dx = 0; dx < 7; ++dx)
                        #pragma unroll
                        for (int p = 0; p < 4; ++p)
                            sim[dx][p] += cen[p] * f[dx + p + 1];
                    xr += 16 * HW;
                    xc += 16 * HW;
                }
            }
            // reduce over 16 channel partitions (lane bits 2..5)
            #pragma unroll
            for (int dx = 0; dx < 7; ++dx)
                #pragma unroll
                for (int p = 0; p < 4; ++p) {
                    float v = sim[dx][p];
                    v += __shfl_xor(v, 4);
                    v += __shfl_xor(v, 8);
                    v += __shfl_xor(v, 16);
                    v += __shfl_xor(v, 32);
                    sim[dx][p] = v;
                }
            if (cp == 0) {
                #pragma unroll
                for (int dx = 0; dx < 7; ++dx)
                    *(f4*)&simRed[dy * 7 + dx][lw0] = *(const f4*)sim[dx];
            }
        }
    }
    __syncthreads();

    // ---------------- Softmax over k=49 ----------------
    {
        const int w  = t & 15;
        const int kc = t >> 4;    // 0..31; kc<7 active
        float sred[7], e[7];
        if (kc < 7) {
            float lmax = -3.0e38f;
            #pragma unroll
            for (int jj = 0; jj < 7; ++jj) {
                float s = simRed[kc * 7 + jj][w];
                sred[jj] = s;
                lmax = fmaxf(lmax, s);
            }
            redBuf[kc][w] = lmax;
        }
        __syncthreads();
        if (kc < 7) {
            float m = redBuf[0][w];
            #pragma unroll
            for (int q = 1; q < 7; ++q) m = fmaxf(m, redBuf[q][w]);
            float ps = 0.f;
            #pragma unroll
            for (int jj = 0; jj < 7; ++jj) {
                e[jj] = __expf(sred[jj] - m);
                ps += e[jj];
            }
            psumBuf[kc][w] = ps;
        }
        __syncthreads();
        if (kc < 7) {
            float l = psumBuf[0][w];
            #pragma unroll
            for (int q = 1; q < 7; ++q) l += psumBuf[q][w];
            float rinv = 1.0f / l;
            #pragma unroll
            for (int jj = 0; jj < 7; ++jj)
                attnBuf[kc * 7 + jj][w] = e[jj] * rinv;
        }
    }
    __syncthreads();

    // ---------------- Phase B: out[c][w] = sum_k attn[k]*x[c,nbr] ----------------
    {
        const int w4 = t & 3;
        const int ci = t >> 2;           // 0..127 -> 2 channels each
        const int lw0 = w4 * 4;
        const int w0g = wbase + lw0;
        const int c0 = ci * 2;
        const bool hasL = (w0g != 0);
        const bool hasR = (w0g != 60);

        float acc[2][4];
        #pragma unroll
        for (int ch = 0; ch < 2; ++ch)
            #pragma unroll
            for (int p = 0; p < 4; ++p) acc[ch][p] = 0.f;

        for (int dy = 0; dy < 7; ++dy) {
            const int row = h + dy - 3;
            if (row < 0 || row >= Hdim) continue;   // block-uniform
            float a[7][4];
            #pragma unroll
            for (int dx = 0; dx < 7; ++dx) {
                f4 v = *(const f4*)&attnBuf[dy * 7 + dx][lw0];
                a[dx][0]=v.x; a[dx][1]=v.y; a[dx][2]=v.z; a[dx][3]=v.w;
            }
            const float* xr = xb + (size_t)c0 * HW + row * Wdim;
            #pragma unroll
            for (int ch = 0; ch < 2; ++ch) {
                float f[12];
                if (hasL) {
                    f4 v = *(const f4*)(xr + w0g - 4);
                    f[0]=v.x; f[1]=v.y; f[2]=v.z; f[3]=v.w;
                } else { f[0]=0.f; f[1]=0.f; f[2]=0.f; f[3]=0.f; }
                {
                    f4 v = *(const f4*)(xr + w0g);
                    f[4]=v.x; f[5]=v.y; f[6]=v.z; f[7]=v.w;
                }
                if (hasR) {
                    f4 v = *(const f4*)(xr + w0g + 4);
                    f[8]=v.x; f[9]=v.y; f[10]=v.z; f[11]=v.w;
                } else { f[8]=0.f; f[9]=0.f; f[10]=0.f; f[11]=0.f; }
                #pragma unroll
                for (int dx = 0; dx < 7; ++dx)
                    #pragma unroll
                    for (int p = 0; p < 4; ++p)
                        acc[ch][p] += a[dx][p] * f[dx + p + 1];
                xr += HW;
            }
        }

        float* ob = out + (size_t)b * (Cdim * HW) + h * Wdim + wbase;
        #pragma unroll
        for (int ch = 0; ch < 2; ++ch)
            *(f4*)(ob + (size_t)(c0 + ch) * HW + lw0) = *(const f4*)acc[ch];
    }
}

extern "C" void kernel_launch(void* const* d_in, const int* in_sizes, int n_in,
                              void* d_out, int out_size, void* d_ws, size_t ws_size,
                              hipStream_t stream)
{
    const float* x = (const float*)d_in[0];
    float* out = (float*)d_out;
    selfattn_kernel<<<dim3(1024), 512, 0, stream>>>(x, out);
}

// Round 7
// 238.135 us; speedup vs baseline: 1.4545x; 1.4545x over previous
//
#include <hip/hip_runtime.h>

typedef float f4 __attribute__((ext_vector_type(4)));

#define Hdim 64
#define Wdim 64
#define Cdim 256
#define HW (Hdim * Wdim)

// Round-6 structure (w-quarter split, 1024 blocks) but launch_bounds(512,4):
// round 6's (512,8) forced VGPR to 32 -> massive scratch spill (WRITE 628MB).
// (512,4) lets the allocator land at its natural ~56 VGPR (round-5 value);
// 56 <= 64 still permits 8 waves/SIMD, so the 1024-block grid can fill the CU.
// XCD decode: xcd = bid&7 owns (batch, 32-row h-band); 2.4MB < 4MB L2.
__global__ __launch_bounds__(512, 4) void selfattn_kernel(const float* __restrict__ x,
                                                          float* __restrict__ out)
{
    const int bid = blockIdx.x;
    const int k   = bid & 7;
    const int seq = bid >> 3;            // 0..127
    const int b   = k >> 1;              // batch
    const int h   = (k & 1) * 32 + (seq >> 2);
    const int wbase = (seq & 3) * 16;    // w-quarter
    const int t = threadIdx.x;           // 0..511

    __shared__ float simRed[49][16];
    __shared__ float attnBuf[49][16];
    __shared__ float redBuf[7][16];
    __shared__ float psumBuf[7][16];

    const float* xb = x + (size_t)b * (Cdim * HW);

    // ---------------- Phase A: sim[k][w] ----------------
    // thread = (w4: lane bits 0..1, cp: lane bits 2..5, dy: wave).
    // channel for iter i: c = i*16 + cp. f[j] <-> row position (w0g - 4 + j).
    {
        const int w4 = t & 3;            // w-group of 4 (16 wide)
        const int cp = (t >> 2) & 15;    // channel partition
        const int dy = t >> 6;           // wave-uniform; dy==7 idle
        const int lw0 = w4 * 4;
        const int w0g = wbase + lw0;

        if (dy < 7) {
            float sim[7][4];
            #pragma unroll
            for (int dx = 0; dx < 7; ++dx)
                #pragma unroll
                for (int p = 0; p < 4; ++p) sim[dx][p] = 0.f;

            const int row = h + dy - 3;
            if (row >= 0 && row < Hdim) {
                const bool hasL = (w0g != 0);
                const bool hasR = (w0g != 60);
                const float* xr = xb + (size_t)cp * HW + row * Wdim;
                const float* xc = xb + (size_t)cp * HW + h   * Wdim;
                for (int i = 0; i < 16; ++i) {
                    float f[12];
                    if (hasL) {
                        f4 v = *(const f4*)(xr + w0g - 4);
                        f[0]=v.x; f[1]=v.y; f[2]=v.z; f[3]=v.w;
                    } else { f[0]=0.f; f[1]=0.f; f[2]=0.f; f[3]=0.f; }
                    {
                        f4 v = *(const f4*)(xr + w0g);
                        f[4]=v.x; f[5]=v.y; f[6]=v.z; f[7]=v.w;
                    }
                    if (hasR) {
                        f4 v = *(const f4*)(xr + w0g + 4);
                        f[8]=v.x; f[9]=v.y; f[10]=v.z; f[11]=v.w;
                    } else { f[8]=0.f; f[9]=0.f; f[10]=0.f; f[11]=0.f; }
                    f4 cen = *(const f4*)(xc + w0g);
                    #pragma unroll
                    for (int dx = 0; dx < 7; ++dx)
                        #pragma unroll
                        for (int p = 0; p < 4; ++p)
                            sim[dx][p] += cen[p] * f[dx + p + 1];
                    xr += 16 * HW;
                    xc += 16 * HW;
                }
            }
            // reduce over 16 channel partitions (lane bits 2..5)
            #pragma unroll
            for (int dx = 0; dx < 7; ++dx)
                #pragma unroll
                for (int p = 0; p < 4; ++p) {
                    float v = sim[dx][p];
                    v += __shfl_xor(v, 4);
                    v += __shfl_xor(v, 8);
                    v += __shfl_xor(v, 16);
                    v += __shfl_xor(v, 32);
                    sim[dx][p] = v;
                }
            if (cp == 0) {
                #pragma unroll
                for (int dx = 0; dx < 7; ++dx)
                    *(f4*)&simRed[dy * 7 + dx][lw0] = *(const f4*)sim[dx];
            }
        }
    }
    __syncthreads();

    // ---------------- Softmax over k=49 ----------------
    {
        const int w  = t & 15;
        const int kc = t >> 4;    // 0..31; kc<7 active
        float sred[7], e[7];
        if (kc < 7) {
            float lmax = -3.0e38f;
            #pragma unroll
            for (int jj = 0; jj < 7; ++jj) {
                float s = simRed[kc * 7 + jj][w];
                sred[jj] = s;
                lmax = fmaxf(lmax, s);
            }
            redBuf[kc][w] = lmax;
        }
        __syncthreads();
        if (kc < 7) {
            float m = redBuf[0][w];
            #pragma unroll
            for (int q = 1; q < 7; ++q) m = fmaxf(m, redBuf[q][w]);
            float ps = 0.f;
            #pragma unroll
            for (int jj = 0; jj < 7; ++jj) {
                e[jj] = __expf(sred[jj] - m);
                ps += e[jj];
            }
            psumBuf[kc][w] = ps;
        }
        __syncthreads();
        if (kc < 7) {
            float l = psumBuf[0][w];
            #pragma unroll
            for (int q = 1; q < 7; ++q) l += psumBuf[q][w];
            float rinv = 1.0f / l;
            #pragma unroll
            for (int jj = 0; jj < 7; ++jj)
                attnBuf[kc * 7 + jj][w] = e[jj] * rinv;
        }
    }
    __syncthreads();

    // ---------------- Phase B: out[c][w] = sum_k attn[k]*x[c,nbr] ----------------
    {
        const int w4 = t & 3;
        const int ci = t >> 2;           // 0..127 -> 2 channels each
        const int lw0 = w4 * 4;
        const int w0g = wbase + lw0;
        const int c0 = ci * 2;
        const bool hasL = (w0g != 0);
        const bool hasR = (w0g != 60);

        float acc[2][4];
        #pragma unroll
        for (int ch = 0; ch < 2; ++ch)
            #pragma unroll
            for (int p = 0; p < 4; ++p) acc[ch][p] = 0.f;

        for (int dy = 0; dy < 7; ++dy) {
            const int row = h + dy - 3;
            if (row < 0 || row >= Hdim) continue;   // block-uniform
            float a[7][4];
            #pragma unroll
            for (int dx = 0; dx < 7; ++dx) {
                f4 v = *(const f4*)&attnBuf[dy * 7 + dx][lw0];
                a[dx][0]=v.x; a[dx][1]=v.y; a[dx][2]=v.z; a[dx][3]=v.w;
            }
            const float* xr = xb + (size_t)c0 * HW + row * Wdim;
            #pragma unroll
            for (int ch = 0; ch < 2; ++ch) {
                float f[12];
                if (hasL) {
                    f4 v = *(const f4*)(xr + w0g - 4);
                    f[0]=v.x; f[1]=v.y; f[2]=v.z; f[3]=v.w;
                } else { f[0]=0.f; f[1]=0.f; f[2]=0.f; f[3]=0.f; }
                {
                    f4 v = *(const f4*)(xr + w0g);
                    f[4]=v.x; f[5]=v.y; f[6]=v.z; f[7]=v.w;
                }
                if (hasR) {
                    f4 v = *(const f4*)(xr + w0g + 4);
                    f[8]=v.x; f[9]=v.y; f[10]=v.z; f[11]=v.w;
                } else { f[8]=0.f; f[9]=0.f; f[10]=0.f; f[11]=0.f; }
                #pragma unroll
                for (int dx = 0; dx < 7; ++dx)
                    #pragma unroll
                    for (int p = 0; p < 4; ++p)
                        acc[ch][p] += a[dx][p] * f[dx + p + 1];
                xr += HW;
            }
        }

        float* ob = out + (size_t)b * (Cdim * HW) + h * Wdim + wbase;
        #pragma unroll
        for (int ch = 0; ch < 2; ++ch)
            *(f4*)(ob + (size_t)(c0 + ch) * HW + lw0) = *(const f4*)acc[ch];
    }
}

extern "C" void kernel_launch(void* const* d_in, const int* in_sizes, int n_in,
                              void* d_out, int out_size, void* d_ws, size_t ws_size,
                              hipStream_t stream)
{
    const float* x = (const float*)d_in[0];
    float* out = (float*)d_out;
    selfattn_kernel<<<dim3(1024), 512, 0, stream>>>(x, out);
}

// Round 8
// 81.738 us; speedup vs baseline: 4.2375x; 2.9134x over previous
//
#include <hip/hip_runtime.h>

typedef float f4 __attribute__((ext_vector_type(4)));

#define Hdim 64
#define Wdim 64
#define Cdim 256
#define HW (Hdim * Wdim)

// 1024 blocks x 512 threads, w-quarter split, XCD decode (bid&7 owns a
// (batch, 32-row h-band): 2.4MB working set < 4MB per-XCD L2).
// PLAIN launch_bounds(512): the 2nd arg (min waves/EU = N) sets a hard
// VGPR budget ~256/N on this toolchain and FORCES SPILLS when natural
// demand exceeds it (r6: N=8->32 VGPR, 628MB scratch; r7: N=4->64, 417MB).
// Natural allocation never spilled (r2-r5). #pragma unroll 1 on the
// f[12]-carrying loops keeps natural demand near 56-64 so the HARDWARE
// can schedule 8 waves/SIMD (m69: boundary at 64) from the 1024-block grid.
__global__ __launch_bounds__(512) void selfattn_kernel(const float* __restrict__ x,
                                                       float* __restrict__ out)
{
    const int bid = blockIdx.x;
    const int k   = bid & 7;
    const int seq = bid >> 3;            // 0..127
    const int b   = k >> 1;              // batch
    const int h   = (k & 1) * 32 + (seq >> 2);
    const int wbase = (seq & 3) * 16;    // w-quarter
    const int t = threadIdx.x;           // 0..511

    __shared__ float simRed[49][16];
    __shared__ float attnBuf[49][16];
    __shared__ float redBuf[7][16];
    __shared__ float psumBuf[7][16];

    const float* xb = x + (size_t)b * (Cdim * HW);

    // ---------------- Phase A: sim[k][w] ----------------
    // thread = (w4: lane bits 0..1, cp: lane bits 2..5, dy: wave).
    // channel for iter i: c = i*16 + cp. f[j] <-> row position (w0g - 4 + j).
    {
        const int w4 = t & 3;            // w-group of 4 (16 wide)
        const int cp = (t >> 2) & 15;    // channel partition
        const int dy = t >> 6;           // wave-uniform; dy==7 idle
        const int lw0 = w4 * 4;
        const int w0g = wbase + lw0;

        if (dy < 7) {
            float sim[7][4];
            #pragma unroll
            for (int dx = 0; dx < 7; ++dx)
                #pragma unroll
                for (int p = 0; p < 4; ++p) sim[dx][p] = 0.f;

            const int row = h + dy - 3;
            if (row >= 0 && row < Hdim) {
                const bool hasL = (w0g != 0);
                const bool hasR = (w0g != 60);
                const float* xr = xb + (size_t)cp * HW + row * Wdim;
                const float* xc = xb + (size_t)cp * HW + h   * Wdim;
                #pragma unroll 1
                for (int i = 0; i < 16; ++i) {
                    float f[12];
                    if (hasL) {
                        f4 v = *(const f4*)(xr + w0g - 4);
                        f[0]=v.x; f[1]=v.y; f[2]=v.z; f[3]=v.w;
                    } else { f[0]=0.f; f[1]=0.f; f[2]=0.f; f[3]=0.f; }
                    {
                        f4 v = *(const f4*)(xr + w0g);
                        f[4]=v.x; f[5]=v.y; f[6]=v.z; f[7]=v.w;
                    }
                    if (hasR) {
                        f4 v = *(const f4*)(xr + w0g + 4);
                        f[8]=v.x; f[9]=v.y; f[10]=v.z; f[11]=v.w;
                    } else { f[8]=0.f; f[9]=0.f; f[10]=0.f; f[11]=0.f; }
                    f4 cen = *(const f4*)(xc + w0g);
                    #pragma unroll
                    for (int dx = 0; dx < 7; ++dx)
                        #pragma unroll
                        for (int p = 0; p < 4; ++p)
                            sim[dx][p] += cen[p] * f[dx + p + 1];
                    xr += 16 * HW;
                    xc += 16 * HW;
                }
            }
            // reduce over 16 channel partitions (lane bits 2..5)
            #pragma unroll
            for (int dx = 0; dx < 7; ++dx)
                #pragma unroll
                for (int p = 0; p < 4; ++p) {
                    float v = sim[dx][p];
                    v += __shfl_xor(v, 4);
                    v += __shfl_xor(v, 8);
                    v += __shfl_xor(v, 16);
                    v += __shfl_xor(v, 32);
                    sim[dx][p] = v;
                }
            if (cp == 0) {
                #pragma unroll
                for (int dx = 0; dx < 7; ++dx)
                    *(f4*)&simRed[dy * 7 + dx][lw0] = *(const f4*)sim[dx];
            }
        }
    }
    __syncthreads();

    // ---------------- Softmax over k=49 ----------------
    {
        const int w  = t & 15;
        const int kc = t >> 4;    // 0..31; kc<7 active
        float sred[7], e[7];
        if (kc < 7) {
            float lmax = -3.0e38f;
            #pragma unroll
            for (int jj = 0; jj < 7; ++jj) {
                float s = simRed[kc * 7 + jj][w];
                sred[jj] = s;
                lmax = fmaxf(lmax, s);
            }
            redBuf[kc][w] = lmax;
        }
        __syncthreads();
        if (kc < 7) {
            float m = redBuf[0][w];
            #pragma unroll
            for (int q = 1; q < 7; ++q) m = fmaxf(m, redBuf[q][w]);
            float ps = 0.f;
            #pragma unroll
            for (int jj = 0; jj < 7; ++jj) {
                e[jj] = __expf(sred[jj] - m);
                ps += e[jj];
            }
            psumBuf[kc][w] = ps;
        }
        __syncthreads();
        if (kc < 7) {
            float l = psumBuf[0][w];
            #pragma unroll
            for (int q = 1; q < 7; ++q) l += psumBuf[q][w];
            float rinv = 1.0f / l;
            #pragma unroll
            for (int jj = 0; jj < 7; ++jj)
                attnBuf[kc * 7 + jj][w] = e[jj] * rinv;
        }
    }
    __syncthreads();

    // ---------------- Phase B: out[c][w] = sum_k attn[k]*x[c,nbr] ----------------
    {
        const int w4 = t & 3;
        const int ci = t >> 2;           // 0..127 -> 2 channels each
        const int lw0 = w4 * 4;
        const int w0g = wbase + lw0;
        const int c0 = ci * 2;
        const bool hasL = (w0g != 0);
        const bool hasR = (w0g != 60);

        float acc[2][4];
        #pragma unroll
        for (int ch = 0; ch < 2; ++ch)
            #pragma unroll
            for (int p = 0; p < 4; ++p) acc[ch][p] = 0.f;

        #pragma unroll 1
        for (int dy = 0; dy < 7; ++dy) {
            const int row = h + dy - 3;
            if (row < 0 || row >= Hdim) continue;   // block-uniform
            float a[7][4];
            #pragma unroll
            for (int dx = 0; dx < 7; ++dx) {
                f4 v = *(const f4*)&attnBuf[dy * 7 + dx][lw0];
                a[dx][0]=v.x; a[dx][1]=v.y; a[dx][2]=v.z; a[dx][3]=v.w;
            }
            const float* xr = xb + (size_t)c0 * HW + row * Wdim;
            #pragma unroll 1
            for (int ch = 0; ch < 2; ++ch) {
                float f[12];
                if (hasL) {
                    f4 v = *(const f4*)(xr + w0g - 4);
                    f[0]=v.x; f[1]=v.y; f[2]=v.z; f[3]=v.w;
                } else { f[0]=0.f; f[1]=0.f; f[2]=0.f; f[3]=0.f; }
                {
                    f4 v = *(const f4*)(xr + w0g);
                    f[4]=v.x; f[5]=v.y; f[6]=v.z; f[7]=v.w;
                }
                if (hasR) {
                    f4 v = *(const f4*)(xr + w0g + 4);
                    f[8]=v.x; f[9]=v.y; f[10]=v.z; f[11]=v.w;
                } else { f[8]=0.f; f[9]=0.f; f[10]=0.f; f[11]=0.f; }
                #pragma unroll
                for (int dx = 0; dx < 7; ++dx)
                    #pragma unroll
                    for (int p = 0; p < 4; ++p)
                        acc[ch][p] += a[dx][p] * f[dx + p + 1];
                xr += HW;
            }
        }

        float* ob = out + (size_t)b * (Cdim * HW) + h * Wdim + wbase;
        #pragma unroll
        for (int ch = 0; ch < 2; ++ch)
            *(f4*)(ob + (size_t)(c0 + ch) * HW + lw0) = *(const f4*)acc[ch];
    }
}

extern "C" void kernel_launch(void* const* d_in, const int* in_sizes, int n_in,
                              void* d_out, int out_size, void* d_ws, size_t ws_size,
                              hipStream_t stream)
{
    const float* x = (const float*)d_in[0];
    float* out = (float*)d_out;
    selfattn_kernel<<<dim3(1024), 512, 0, stream>>>(x, out);
}

// Round 9
// 78.207 us; speedup vs baseline: 4.4288x; 1.0451x over previous
//
#include <hip/hip_runtime.h>

typedef float f4 __attribute__((ext_vector_type(4)));

#define Hdim 64
#define Wdim 64
#define Cdim 256
#define HW (Hdim * Wdim)

// 1024 blocks x 512 threads, w-quarter split, XCD decode (bid&7 owns a
// (batch, 32-row h-band): 2.4MB working set < 4MB per-XCD L2).
// launch_bounds(512, 2): VGPR budget ~128. Ledger: (512,4) caps at 64 and
// the fully-unrolled 16-iter phase-A loop demands ~70-90 -> forced scratch
// spill (r7: WRITE 417MB). (512,8) -> 32 VGPR, worse (r6). unroll-1 makes
// the allocator demote arrays to LDS (r8: VGPR 36, +16KB LDS, 1.5M bank
// conflicts). Budget 128 lets the compiler keep its full-unroll load
// hoisting (good memory ILP) with zero spill; 1024-block grid then gives
// 4-5 waves/SIMD.
__global__ __launch_bounds__(512, 2) void selfattn_kernel(const float* __restrict__ x,
                                                          float* __restrict__ out)
{
    const int bid = blockIdx.x;
    const int k   = bid & 7;
    const int seq = bid >> 3;            // 0..127
    const int b   = k >> 1;              // batch
    const int h   = (k & 1) * 32 + (seq >> 2);
    const int wbase = (seq & 3) * 16;    // w-quarter
    const int t = threadIdx.x;           // 0..511

    __shared__ float simRed[49][16];
    __shared__ float attnBuf[49][16];
    __shared__ float redBuf[7][16];
    __shared__ float psumBuf[7][16];

    const float* xb = x + (size_t)b * (Cdim * HW);

    // ---------------- Phase A: sim[k][w] ----------------
    // thread = (w4: lane bits 0..1, cp: lane bits 2..5, dy: wave).
    // channel for iter i: c = i*16 + cp. f[j] <-> row position (w0g - 4 + j).
    {
        const int w4 = t & 3;            // w-group of 4 (16 wide)
        const int cp = (t >> 2) & 15;    // channel partition
        const int dy = t >> 6;           // wave-uniform; dy==7 idle
        const int lw0 = w4 * 4;
        const int w0g = wbase + lw0;

        if (dy < 7) {
            float sim[7][4];
            #pragma unroll
            for (int dx = 0; dx < 7; ++dx)
                #pragma unroll
                for (int p = 0; p < 4; ++p) sim[dx][p] = 0.f;

            const int row = h + dy - 3;
            if (row >= 0 && row < Hdim) {
                const bool hasL = (w0g != 0);
                const bool hasR = (w0g != 60);
                const float* xr = xb + (size_t)cp * HW + row * Wdim;
                const float* xc = xb + (size_t)cp * HW + h   * Wdim;
                for (int i = 0; i < 16; ++i) {
                    float f[12];
                    if (hasL) {
                        f4 v = *(const f4*)(xr + w0g - 4);
                        f[0]=v.x; f[1]=v.y; f[2]=v.z; f[3]=v.w;
                    } else { f[0]=0.f; f[1]=0.f; f[2]=0.f; f[3]=0.f; }
                    {
                        f4 v = *(const f4*)(xr + w0g);
                        f[4]=v.x; f[5]=v.y; f[6]=v.z; f[7]=v.w;
                    }
                    if (hasR) {
                        f4 v = *(const f4*)(xr + w0g + 4);
                        f[8]=v.x; f[9]=v.y; f[10]=v.z; f[11]=v.w;
                    } else { f[8]=0.f; f[9]=0.f; f[10]=0.f; f[11]=0.f; }
                    f4 cen = *(const f4*)(xc + w0g);
                    #pragma unroll
                    for (int dx = 0; dx < 7; ++dx)
                        #pragma unroll
                        for (int p = 0; p < 4; ++p)
                            sim[dx][p] += cen[p] * f[dx + p + 1];
                    xr += 16 * HW;
                    xc += 16 * HW;
                }
            }
            // reduce over 16 channel partitions (lane bits 2..5)
            #pragma unroll
            for (int dx = 0; dx < 7; ++dx)
                #pragma unroll
                for (int p = 0; p < 4; ++p) {
                    float v = sim[dx][p];
                    v += __shfl_xor(v, 4);
                    v += __shfl_xor(v, 8);
                    v += __shfl_xor(v, 16);
                    v += __shfl_xor(v, 32);
                    sim[dx][p] = v;
                }
            if (cp == 0) {
                #pragma unroll
                for (int dx = 0; dx < 7; ++dx)
                    *(f4*)&simRed[dy * 7 + dx][lw0] = *(const f4*)sim[dx];
            }
        }
    }
    __syncthreads();

    // ---------------- Softmax over k=49 ----------------
    {
        const int w  = t & 15;
        const int kc = t >> 4;    // 0..31; kc<7 active
        float sred[7], e[7];
        if (kc < 7) {
            float lmax = -3.0e38f;
            #pragma unroll
            for (int jj = 0; jj < 7; ++jj) {
                float s = simRed[kc * 7 + jj][w];
                sred[jj] = s;
                lmax = fmaxf(lmax, s);
            }
            redBuf[kc][w] = lmax;
        }
        __syncthreads();
        if (kc < 7) {
            float m = redBuf[0][w];
            #pragma unroll
            for (int q = 1; q < 7; ++q) m = fmaxf(m, redBuf[q][w]);
            float ps = 0.f;
            #pragma unroll
            for (int jj = 0; jj < 7; ++jj) {
                e[jj] = __expf(sred[jj] - m);
                ps += e[jj];
            }
            psumBuf[kc][w] = ps;
        }
        __syncthreads();
        if (kc < 7) {
            float l = psumBuf[0][w];
            #pragma unroll
            for (int q = 1; q < 7; ++q) l += psumBuf[q][w];
            float rinv = 1.0f / l;
            #pragma unroll
            for (int jj = 0; jj < 7; ++jj)
                attnBuf[kc * 7 + jj][w] = e[jj] * rinv;
        }
    }
    __syncthreads();

    // ---------------- Phase B: out[c][w] = sum_k attn[k]*x[c,nbr] ----------------
    {
        const int w4 = t & 3;
        const int ci = t >> 2;           // 0..127 -> 2 channels each
        const int lw0 = w4 * 4;
        const int w0g = wbase + lw0;
        const int c0 = ci * 2;
        const bool hasL = (w0g != 0);
        const bool hasR = (w0g != 60);

        float acc[2][4];
        #pragma unroll
        for (int ch = 0; ch < 2; ++ch)
            #pragma unroll
            for (int p = 0; p < 4; ++p) acc[ch][p] = 0.f;

        for (int dy = 0; dy < 7; ++dy) {
            const int row = h + dy - 3;
            if (row < 0 || row >= Hdim) continue;   // block-uniform
            float a[7][4];
            #pragma unroll
            for (int dx = 0; dx < 7; ++dx) {
                f4 v = *(const f4*)&attnBuf[dy * 7 + dx][lw0];
                a[dx][0]=v.x; a[dx][1]=v.y; a[dx][2]=v.z; a[dx][3]=v.w;
            }
            const float* xr = xb + (size_t)c0 * HW + row * Wdim;
            #pragma unroll
            for (int ch = 0; ch < 2; ++ch) {
                float f[12];
                if (hasL) {
                    f4 v = *(const f4*)(xr + w0g - 4);
                    f[0]=v.x; f[1]=v.y; f[2]=v.z; f[3]=v.w;
                } else { f[0]=0.f; f[1]=0.f; f[2]=0.f; f[3]=0.f; }
                {
                    f4 v = *(const f4*)(xr + w0g);
                    f[4]=v.x; f[5]=v.y; f[6]=v.z; f[7]=v.w;
                }
                if (hasR) {
                    f4 v = *(const f4*)(xr + w0g + 4);
                    f[8]=v.x; f[9]=v.y; f[10]=v.z; f[11]=v.w;
                } else { f[8]=0.f; f[9]=0.f; f[10]=0.f; f[11]=0.f; }
                #pragma unroll
                for (int dx = 0; dx < 7; ++dx)
                    #pragma unroll
                    for (int p = 0; p < 4; ++p)
                        acc[ch][p] += a[dx][p] * f[dx + p + 1];
                xr += HW;
            }
        }

        float* ob = out + (size_t)b * (Cdim * HW) + h * Wdim + wbase;
        #pragma unroll
        for (int ch = 0; ch < 2; ++ch)
            *(f4*)(ob + (size_t)(c0 + ch) * HW + lw0) = *(const f4*)acc[ch];
    }
}

extern "C" void kernel_launch(void* const* d_in, const int* in_sizes, int n_in,
                              void* d_out, int out_size, void* d_ws, size_t ws_size,
                              hipStream_t stream)
{
    const float* x = (const float*)d_in[0];
    float* out = (float*)d_out;
    selfattn_kernel<<<dim3(1024), 512, 0, stream>>>(x, out);
}

// Round 10
// 48.456 us; speedup vs baseline: 7.1480x; 1.6140x over previous
//
#include <hip/hip_runtime.h>

typedef float f4 __attribute__((ext_vector_type(4)));

#define Hdim 64
#define Wdim 64
#define Cdim 256
#define HW (Hdim * Wdim)

// ============================================================================
// Two-kernel split. Fused w-quarter kernels spill at every launch_bounds
// (r6-r9 ledger: forced budgets 32/64/128 all produce scratch traffic because
// phase-A window + sim accs + phase-B state exceed the budget once the short
// channel loop fully unrolls). Champion r5 (40.3us, VGPR 56) is grid-limited
// to 4096 waves (34% occupancy). Splitting sim-partials (K1) from
// softmax+out (K2) gives 1024 small blocks each, register-lean kernels,
// ~7-8K waves -> ~80% occupancy, half-length dependency chains.
// XCD decode in both: bid&7 owns (batch, 32-row h-band); working set
// 2.4MB < 4MB per-XCD L2 (r4: FETCH 108MB -> 9MB).
// ============================================================================

// K1: partial sim over a 128-channel half. 448 thr = 7 dy-waves, all active.
// No LDS, no barriers. ws layout: [bid][49][32] f32.
__global__ __launch_bounds__(448) void k1_sim(const float* __restrict__ x,
                                              float* __restrict__ ws)
{
    const int bid = blockIdx.x;          // 0..1023
    const int k   = bid & 7;
    const int seq = bid >> 3;            // 0..127
    const int b   = k >> 1;
    const int h   = (k & 1) * 32 + (seq >> 2);
    const int wh  = (seq >> 1) & 1;
    const int chalf = seq & 1;
    const int wbase = wh * 32;
    const int cbase = chalf * 128;
    const int t = threadIdx.x;           // 0..447

    const int w4 = t & 7;                // w-group of 4 (32 wide)
    const int cp = (t >> 3) & 7;         // channel partition
    const int dy = t >> 6;               // 0..6, wave-uniform
    const int lw0 = w4 * 4;
    const int w0g = wbase + lw0;

    const float* xb = x + (size_t)b * (Cdim * HW);

    float sim[7][4];
    #pragma unroll
    for (int dx = 0; dx < 7; ++dx)
        #pragma unroll
        for (int p = 0; p < 4; ++p) sim[dx][p] = 0.f;

    const int row = h + dy - 3;
    if (row >= 0 && row < Hdim) {
        const bool hasL = (w0g != 0);
        const bool hasR = (w0g != 60);
        const float* xr = xb + (size_t)(cbase + cp) * HW + row * Wdim;
        const float* xc = xb + (size_t)(cbase + cp) * HW + h   * Wdim;
        #pragma unroll 2
        for (int i = 0; i < 16; ++i) {
            float f[12];
            if (hasL) {
                f4 v = *(const f4*)(xr + w0g - 4);
                f[0]=v.x; f[1]=v.y; f[2]=v.z; f[3]=v.w;
            } else { f[0]=0.f; f[1]=0.f; f[2]=0.f; f[3]=0.f; }
            {
                f4 v = *(const f4*)(xr + w0g);
                f[4]=v.x; f[5]=v.y; f[6]=v.z; f[7]=v.w;
            }
            if (hasR) {
                f4 v = *(const f4*)(xr + w0g + 4);
                f[8]=v.x; f[9]=v.y; f[10]=v.z; f[11]=v.w;
            } else { f[8]=0.f; f[9]=0.f; f[10]=0.f; f[11]=0.f; }
            f4 cen = *(const f4*)(xc + w0g);
            #pragma unroll
            for (int dx = 0; dx < 7; ++dx)
                #pragma unroll
                for (int p = 0; p < 4; ++p)
                    sim[dx][p] += cen[p] * f[dx + p + 1];
            xr += 8 * HW;
            xc += 8 * HW;
        }
    }
    // reduce over 8 channel partitions (lane bits 3..5)
    #pragma unroll
    for (int dx = 0; dx < 7; ++dx)
        #pragma unroll
        for (int p = 0; p < 4; ++p) {
            float v = sim[dx][p];
            v += __shfl_xor(v, 8);
            v += __shfl_xor(v, 16);
            v += __shfl_xor(v, 32);
            sim[dx][p] = v;
        }
    if (cp == 0) {
        float* wp = ws + (size_t)bid * (49 * 32);
        #pragma unroll
        for (int dx = 0; dx < 7; ++dx)
            *(f4*)(wp + (dy * 7 + dx) * 32 + lw0) = *(const f4*)sim[dx];
    }
}

// K2: sum partials -> softmax -> phase B for a 128-channel half.
__global__ __launch_bounds__(512) void k2_out(const float* __restrict__ x,
                                              const float* __restrict__ ws,
                                              float* __restrict__ out)
{
    const int bid = blockIdx.x;          // 0..1023
    const int k   = bid & 7;
    const int seq = bid >> 3;
    const int b   = k >> 1;
    const int h   = (k & 1) * 32 + (seq >> 2);
    const int wh  = (seq >> 1) & 1;
    const int chalf = seq & 1;
    const int wbase = wh * 32;
    const int cbase = chalf * 128;
    const int t = threadIdx.x;           // 0..511

    __shared__ float attnBuf[49][32];
    __shared__ float redBuf[7][32];
    __shared__ float psumBuf[7][32];

    const float* xb = x + (size_t)b * (Cdim * HW);

    // K1 bid for (b,h,wh,chalf'): seq' = (h&31)*4 + wh*2 + ch'; bid' = seq'*8 + k
    const int seqBase = ((h & 31) * 4 + wh * 2);
    const float* p0 = ws + (size_t)((seqBase + 0) * 8 + k) * (49 * 32);
    const float* p1 = ws + (size_t)((seqBase + 1) * 8 + k) * (49 * 32);

    // ---------------- Softmax over k=49 ----------------
    {
        const int w  = t & 31;
        const int kc = t >> 5;    // 0..15; kc<7 active
        float sred[7], e[7];
        if (kc < 7) {
            float lmax = -3.0e38f;
            #pragma unroll
            for (int jj = 0; jj < 7; ++jj) {
                const int idx = (kc * 7 + jj) * 32 + w;
                float s = p0[idx] + p1[idx];
                sred[jj] = s;
                lmax = fmaxf(lmax, s);
            }
            redBuf[kc][w] = lmax;
        }
        __syncthreads();
        if (kc < 7) {
            float m = redBuf[0][w];
            #pragma unroll
            for (int q = 1; q < 7; ++q) m = fmaxf(m, redBuf[q][w]);
            float ps = 0.f;
            #pragma unroll
            for (int jj = 0; jj < 7; ++jj) {
                e[jj] = __expf(sred[jj] - m);
                ps += e[jj];
            }
            psumBuf[kc][w] = ps;
        }
        __syncthreads();
        if (kc < 7) {
            float l = psumBuf[0][w];
            #pragma unroll
            for (int q = 1; q < 7; ++q) l += psumBuf[q][w];
            float rinv = 1.0f / l;
            #pragma unroll
            for (int jj = 0; jj < 7; ++jj)
                attnBuf[kc * 7 + jj][w] = e[jj] * rinv;
        }
    }
    __syncthreads();

    // ---------------- Phase B: out[c][w] = sum_k attn[k]*x[c,nbr] ----------------
    {
        const int w4 = t & 7;
        const int ci = t >> 3;            // 0..63 -> 2 channels each
        const int lw0 = w4 * 4;
        const int w0g = wbase + lw0;
        const int c0 = cbase + ci * 2;
        const bool hasL = (w0g != 0);
        const bool hasR = (w0g != 60);

        float acc[2][4];
        #pragma unroll
        for (int ch = 0; ch < 2; ++ch)
            #pragma unroll
            for (int p = 0; p < 4; ++p) acc[ch][p] = 0.f;

        for (int dy = 0; dy < 7; ++dy) {
            const int row = h + dy - 3;
            if (row < 0 || row >= Hdim) continue;   // block-uniform
            float a[7][4];
            #pragma unroll
            for (int dx = 0; dx < 7; ++dx) {
                f4 v = *(const f4*)&attnBuf[dy * 7 + dx][lw0];
                a[dx][0]=v.x; a[dx][1]=v.y; a[dx][2]=v.z; a[dx][3]=v.w;
            }
            const float* xr = xb + (size_t)c0 * HW + row * Wdim;
            #pragma unroll
            for (int ch = 0; ch < 2; ++ch) {
                float f[12];
                if (hasL) {
                    f4 v = *(const f4*)(xr + w0g - 4);
                    f[0]=v.x; f[1]=v.y; f[2]=v.z; f[3]=v.w;
                } else { f[0]=0.f; f[1]=0.f; f[2]=0.f; f[3]=0.f; }
                {
                    f4 v = *(const f4*)(xr + w0g);
                    f[4]=v.x; f[5]=v.y; f[6]=v.z; f[7]=v.w;
                }
                if (hasR) {
                    f4 v = *(const f4*)(xr + w0g + 4);
                    f[8]=v.x; f[9]=v.y; f[10]=v.z; f[11]=v.w;
                } else { f[8]=0.f; f[9]=0.f; f[10]=0.f; f[11]=0.f; }
                #pragma unroll
                for (int dx = 0; dx < 7; ++dx)
                    #pragma unroll
                    for (int p = 0; p < 4; ++p)
                        acc[ch][p] += a[dx][p] * f[dx + p + 1];
                xr += HW;
            }
        }

        float* ob = out + (size_t)b * (Cdim * HW) + h * Wdim + wbase;
        #pragma unroll
        for (int ch = 0; ch < 2; ++ch)
            *(f4*)(ob + (size_t)(c0 + ch) * HW + lw0) = *(const f4*)acc[ch];
    }
}

// ---------------------------------------------------------------------------
// Fallback: round-5 champion (40.3us) in case ws is too small for partials.
// ---------------------------------------------------------------------------
__global__ __launch_bounds__(512, 4) void selfattn_fallback(const float* __restrict__ x,
                                                            float* __restrict__ out)
{
    const int bid = blockIdx.x;
    const int k   = bid & 7;
    const int seq = bid >> 3;
    const int b   = k >> 1;
    const int h   = (k & 1) * 32 + (seq >> 1);
    const int wbase = (seq & 1) * 32;
    const int t = threadIdx.x;

    __shared__ float simRed[49][32];
    __shared__ float attnBuf[49][32];
    __shared__ float redBuf[7][32];
    __shared__ float psumBuf[7][32];

    const float* xb = x + (size_t)b * (Cdim * HW);

    {
        const int w4 = t & 7;
        const int cp = (t >> 3) & 7;
        const int dy = t >> 6;
        const int lw0 = w4 * 4;
        const int w0g = wbase + lw0;

        if (dy < 7) {
            float sim[7][4];
            #pragma unroll
            for (int dx = 0; dx < 7; ++dx)
                #pragma unroll
                for (int p = 0; p < 4; ++p) sim[dx][p] = 0.f;

            const int row = h + dy - 3;
            if (row >= 0 && row < Hdim) {
                const bool hasL = (w0g != 0);
                const bool hasR = (w0g != 60);
                const float* xr = xb + (size_t)cp * HW + row * Wdim;
                const float* xc = xb + (size_t)cp * HW + h   * Wdim;
                for (int i = 0; i < 32; ++i) {
                    float f[12];
                    if (hasL) {
                        f4 v = *(const f4*)(xr + w0g - 4);
                        f[0]=v.x; f[1]=v.y; f[2]=v.z; f[3]=v.w;
                    } else { f[0]=0.f; f[1]=0.f; f[2]=0.f; f[3]=0.f; }
                    {
                        f4 v = *(const f4*)(xr + w0g);
                        f[4]=v.x; f[5]=v.y; f[6]=v.z; f[7]=v.w;
                    }
                    if (hasR) {
                        f4 v = *(const f4*)(xr + w0g + 4);
                        f[8]=v.x; f[9]=v.y; f[10]=v.z; f[11]=v.w;
                    } else { f[8]=0.f; f[9]=0.f; f[10]=0.f; f[11]=0.f; }
                    f4 cen = *(const f4*)(xc + w0g);
                    #pragma unroll
                    for (int dx = 0; dx < 7; ++dx)
                        #pragma unroll
                        for (int p = 0; p < 4; ++p)
                            sim[dx][p] += cen[p] * f[dx + p + 1];
                    xr += 8 * HW;
                    xc += 8 * HW;
                }
            }
            #pragma unroll
            for (int dx = 0; dx < 7; ++dx)
                #pragma unroll
                for (int p = 0; p < 4; ++p) {
                    float v = sim[dx][p];
                    v += __shfl_xor(v, 8);
                    v += __shfl_xor(v, 16);
                    v += __shfl_xor(v, 32);
                    sim[dx][p] = v;
                }
            if (cp == 0) {
                #pragma unroll
                for (int dx = 0; dx < 7; ++dx)
                    *(f4*)&simRed[dy * 7 + dx][lw0] = *(const f4*)sim[dx];
            }
        }
    }
    __syncthreads();

    {
        const int w  = t & 31;
        const int kc = t >> 5;
        float sred[7], e[7];
        if (kc < 7) {
            float lmax = -3.0e38f;
            #pragma unroll
            for (int jj = 0; jj < 7; ++jj) {
                float s = simRed[kc * 7 + jj][w];
                sred[jj] = s;
                lmax = fmaxf(lmax, s);
            }
            redBuf[kc][w] = lmax;
        }
        __syncthreads();
        if (kc < 7) {
            float m = redBuf[0][w];
            #pragma unroll
            for (int q = 1; q < 7; ++q) m = fmaxf(m, redBuf[q][w]);
            float ps = 0.f;
            #pragma unroll
            for (int jj = 0; jj < 7; ++jj) {
                e[jj] = __expf(sred[jj] - m);
                ps += e[jj];
            }
            psumBuf[kc][w] = ps;
        }
        __syncthreads();
        if (kc < 7) {
            float l = psumBuf[0][w];
            #pragma unroll
            for (int q = 1; q < 7; ++q) l += psumBuf[q][w];
            float rinv = 1.0f / l;
            #pragma unroll
            for (int jj = 0; jj < 7; ++jj)
                attnBuf[kc * 7 + jj][w] = e[jj] * rinv;
        }
    }
    __syncthreads();

    {
        const int w4 = t & 7;
        const int ci = t >> 3;
        const int lw0 = w4 * 4;
        const int w0g = wbase + lw0;
        const int c0 = ci * 4;
        const bool hasL = (w0g != 0);
        const bool hasR = (w0g != 60);

        float acc[4][4];
        #pragma unroll
        for (int ch = 0; ch < 4; ++ch)
            #pragma unroll
            for (int p = 0; p < 4; ++p) acc[ch][p] = 0.f;

        for (int dy = 0; dy < 7; ++dy) {
            const int row = h + dy - 3;
            if (row < 0 || row >= Hdim) continue;
            float a[7][4];
            #pragma unroll
            for (int dx = 0; dx < 7; ++dx) {
                f4 v = *(const f4*)&attnBuf[dy * 7 + dx][lw0];
                a[dx][0]=v.x; a[dx][1]=v.y; a[dx][2]=v.z; a[dx][3]=v.w;
            }
            const float* xr = xb + (size_t)c0 * HW + row * Wdim;
            #pragma unroll
            for (int ch = 0; ch < 4; ++ch) {
                float f[12];
                if (hasL) {
                    f4 v = *(const f4*)(xr + w0g - 4);
                    f[0]=v.x; f[1]=v.y; f[2]=v.z; f[3]=v.w;
                } else { f[0]=0.f; f[1]=0.f; f[2]=0.f; f[3]=0.f; }
                {
                    f4 v = *(const f4*)(xr + w0g);
                    f[4]=v.x; f[5]=v.y; f[6]=v.z; f[7]=v.w;
                }
                if (hasR) {
                    f4 v = *(const f4*)(xr + w0g + 4);
                    f[8]=v.x; f[9]=v.y; f[10]=v.z; f[11]=v.w;
                } else { f[8]=0.f; f[9]=0.f; f[10]=0.f; f[11]=0.f; }
                #pragma unroll
                for (int dx = 0; dx < 7; ++dx)
                    #pragma unroll
                    for (int p = 0; p < 4; ++p)
                        acc[ch][p] += a[dx][p] * f[dx + p + 1];
                xr += HW;
            }
        }

        float* ob = out + (size_t)b * (Cdim * HW) + h * Wdim + wbase;
        #pragma unroll
        for (int ch = 0; ch < 4; ++ch)
            *(f4*)(ob + (size_t)(c0 + ch) * HW + lw0) = *(const f4*)acc[ch];
    }
}

extern "C" void kernel_launch(void* const* d_in, const int* in_sizes, int n_in,
                              void* d_out, int out_size, void* d_ws, size_t ws_size,
                              hipStream_t stream)
{
    const float* x = (const float*)d_in[0];
    float* out = (float*)d_out;
    const size_t need = (size_t)1024 * 49 * 32 * 4;   // 6.4 MB partial sims
    if (ws_size >= need) {
        float* ws = (float*)d_ws;
        k1_sim<<<dim3(1024), 448, 0, stream>>>(x, ws);
        k2_out<<<dim3(1024), 512, 0, stream>>>(x, ws, out);
    } else {
        selfattn_fallback<<<dim3(512), 512, 0, stream>>>(x, out);
    }
}

// Round 11
// 40.017 us; speedup vs baseline: 8.6555x; 1.2109x over previous
//
#include <hip/hip_runtime.h>

typedef float f4 __attribute__((ext_vector_type(4)));

#define Hdim 64
#define Wdim 64
#define Cdim 256
#define HW (Hdim * Wdim)

// r5 champion geometry (512 blocks x 512 thr, w-half, XCD decode: bid&7 owns
// a (batch, 32-row h-band) -> 2.4MB < 4MB per-XCD L2) + ONE change:
// phase A consumes 2 channels per iteration (8 independent global loads in
// flight per iter instead of 4) to double per-wave MLP; sim accumulators are
// shared by both channels so register demand stays ~78 (+unroll2 ~110).
// launch_bounds(512,2): VGPR cap >=128; (512,4)'s cap 64 would force spill.
// #pragma unroll 2 forbids the 16-iter full-unroll register explosion (r7).
__global__ __launch_bounds__(512, 2) void selfattn_kernel(const float* __restrict__ x,
                                                          float* __restrict__ out)
{
    const int bid = blockIdx.x;
    const int k   = bid & 7;
    const int seq = bid >> 3;            // 0..63
    const int b   = k >> 1;              // batch
    const int h   = (k & 1) * 32 + (seq >> 1);
    const int wbase = (seq & 1) * 32;    // w-half
    const int t = threadIdx.x;           // 0..511

    __shared__ float simRed[49][32];
    __shared__ float attnBuf[49][32];
    __shared__ float redBuf[7][32];
    __shared__ float psumBuf[7][32];

    const float* xb = x + (size_t)b * (Cdim * HW);

    // ---------------- Phase A: sim[k][w], 2 channels/iter ----------------
    // thread = (w4: lane bits 0..2, cp: lane bits 3..5, dy: wave).
    // iter i: cA = i*8 + cp (0..127), cB = 128 + i*8 + cp (128..255).
    {
        const int w4 = t & 7;            // w-group of 4 (32 wide)
        const int cp = (t >> 3) & 7;     // channel partition
        const int dy = t >> 6;           // wave-uniform; dy==7 idle
        const int lw0 = w4 * 4;
        const int w0g = wbase + lw0;

        if (dy < 7) {
            float sim[7][4];
            #pragma unroll
            for (int dx = 0; dx < 7; ++dx)
                #pragma unroll
                for (int p = 0; p < 4; ++p) sim[dx][p] = 0.f;

            const int row = h + dy - 3;
            if (row >= 0 && row < Hdim) {
                const bool hasL = (w0g != 0);
                const bool hasR = (w0g != 60);
                const float* xrA = xb + (size_t)cp * HW + row * Wdim;
                const float* xcA = xb + (size_t)cp * HW + h   * Wdim;
                const float* xrB = xrA + (size_t)128 * HW;
                const float* xcB = xcA + (size_t)128 * HW;
                #pragma unroll 2
                for (int i = 0; i < 16; ++i) {
                    float fA[12], fB[12];
                    // window A (channel cA)
                    if (hasL) {
                        f4 v = *(const f4*)(xrA + w0g - 4);
                        fA[0]=v.x; fA[1]=v.y; fA[2]=v.z; fA[3]=v.w;
                    } else { fA[0]=0.f; fA[1]=0.f; fA[2]=0.f; fA[3]=0.f; }
                    {
                        f4 v = *(const f4*)(xrA + w0g);
                        fA[4]=v.x; fA[5]=v.y; fA[6]=v.z; fA[7]=v.w;
                    }
                    if (hasR) {
                        f4 v = *(const f4*)(xrA + w0g + 4);
                        fA[8]=v.x; fA[9]=v.y; fA[10]=v.z; fA[11]=v.w;
                    } else { fA[8]=0.f; fA[9]=0.f; fA[10]=0.f; fA[11]=0.f; }
                    // window B (channel cB)
                    if (hasL) {
                        f4 v = *(const f4*)(xrB + w0g - 4);
                        fB[0]=v.x; fB[1]=v.y; fB[2]=v.z; fB[3]=v.w;
                    } else { fB[0]=0.f; fB[1]=0.f; fB[2]=0.f; fB[3]=0.f; }
                    {
                        f4 v = *(const f4*)(xrB + w0g);
                        fB[4]=v.x; fB[5]=v.y; fB[6]=v.z; fB[7]=v.w;
                    }
                    if (hasR) {
                        f4 v = *(const f4*)(xrB + w0g + 4);
                        fB[8]=v.x; fB[9]=v.y; fB[10]=v.z; fB[11]=v.w;
                    } else { fB[8]=0.f; fB[9]=0.f; fB[10]=0.f; fB[11]=0.f; }
                    f4 cenA = *(const f4*)(xcA + w0g);
                    f4 cenB = *(const f4*)(xcB + w0g);
                    #pragma unroll
                    for (int dx = 0; dx < 7; ++dx)
                        #pragma unroll
                        for (int p = 0; p < 4; ++p)
                            sim[dx][p] += cenA[p] * fA[dx + p + 1]
                                        + cenB[p] * fB[dx + p + 1];
                    xrA += 8 * HW;  xcA += 8 * HW;
                    xrB += 8 * HW;  xcB += 8 * HW;
                }
            }
            // reduce over 8 channel partitions (lane bits 3..5)
            #pragma unroll
            for (int dx = 0; dx < 7; ++dx)
                #pragma unroll
                for (int p = 0; p < 4; ++p) {
                    float v = sim[dx][p];
                    v += __shfl_xor(v, 8);
                    v += __shfl_xor(v, 16);
                    v += __shfl_xor(v, 32);
                    sim[dx][p] = v;
                }
            if (cp == 0) {
                #pragma unroll
                for (int dx = 0; dx < 7; ++dx)
                    *(f4*)&simRed[dy * 7 + dx][lw0] = *(const f4*)sim[dx];
            }
        }
    }
    __syncthreads();

    // ---------------- Softmax over k=49 ----------------
    {
        const int w  = t & 31;
        const int kc = t >> 5;    // 0..15; kc<7 active
        float sred[7], e[7];
        if (kc < 7) {
            float lmax = -3.0e38f;
            #pragma unroll
            for (int jj = 0; jj < 7; ++jj) {
                float s = simRed[kc * 7 + jj][w];
                sred[jj] = s;
                lmax = fmaxf(lmax, s);
            }
            redBuf[kc][w] = lmax;
        }
        __syncthreads();
        if (kc < 7) {
            float m = redBuf[0][w];
            #pragma unroll
            for (int q = 1; q < 7; ++q) m = fmaxf(m, redBuf[q][w]);
            float ps = 0.f;
            #pragma unroll
            for (int jj = 0; jj < 7; ++jj) {
                e[jj] = __expf(sred[jj] - m);
                ps += e[jj];
            }
            psumBuf[kc][w] = ps;
        }
        __syncthreads();
        if (kc < 7) {
            float l = psumBuf[0][w];
            #pragma unroll
            for (int q = 1; q < 7; ++q) l += psumBuf[q][w];
            float rinv = 1.0f / l;
            #pragma unroll
            for (int jj = 0; jj < 7; ++jj)
                attnBuf[kc * 7 + jj][w] = e[jj] * rinv;
        }
    }
    __syncthreads();

    // ---------------- Phase B: out[c][w] = sum_k attn[k]*x[c,nbr] ----------------
    {
        const int w4 = t & 7;
        const int ci = t >> 3;           // 0..63 -> 4 channels each
        const int lw0 = w4 * 4;
        const int w0g = wbase + lw0;
        const int c0 = ci * 4;
        const bool hasL = (w0g != 0);
        const bool hasR = (w0g != 60);

        float acc[4][4];
        #pragma unroll
        for (int ch = 0; ch < 4; ++ch)
            #pragma unroll
            for (int p = 0; p < 4; ++p) acc[ch][p] = 0.f;

        for (int dy = 0; dy < 7; ++dy) {
            const int row = h + dy - 3;
            if (row < 0 || row >= Hdim) continue;   // block-uniform
            float a[7][4];
            #pragma unroll
            for (int dx = 0; dx < 7; ++dx) {
                f4 v = *(const f4*)&attnBuf[dy * 7 + dx][lw0];
                a[dx][0]=v.x; a[dx][1]=v.y; a[dx][2]=v.z; a[dx][3]=v.w;
            }
            const float* xr = xb + (size_t)c0 * HW + row * Wdim;
            #pragma unroll
            for (int ch = 0; ch < 4; ++ch) {
                float f[12];
                if (hasL) {
                    f4 v = *(const f4*)(xr + w0g - 4);
                    f[0]=v.x; f[1]=v.y; f[2]=v.z; f[3]=v.w;
                } else { f[0]=0.f; f[1]=0.f; f[2]=0.f; f[3]=0.f; }
                {
                    f4 v = *(const f4*)(xr + w0g);
                    f[4]=v.x; f[5]=v.y; f[6]=v.z; f[7]=v.w;
                }
                if (hasR) {
                    f4 v = *(const f4*)(xr + w0g + 4);
                    f[8]=v.x; f[9]=v.y; f[10]=v.z; f[11]=v.w;
                } else { f[8]=0.f; f[9]=0.f; f[10]=0.f; f[11]=0.f; }
                #pragma unroll
                for (int dx = 0; dx < 7; ++dx)
                    #pragma unroll
                    for (int p = 0; p < 4; ++p)
                        acc[ch][p] += a[dx][p] * f[dx + p + 1];
                xr += HW;
            }
        }

        float* ob = out + (size_t)b * (Cdim * HW) + h * Wdim + wbase;
        #pragma unroll
        for (int ch = 0; ch < 4; ++ch)
            *(f4*)(ob + (size_t)(c0 + ch) * HW + lw0) = *(const f4*)acc[ch];
    }
}

extern "C" void kernel_launch(void* const* d_in, const int* in_sizes, int n_in,
                              void* d_out, int out_size, void* d_ws, size_t ws_size,
                              hipStream_t stream)
{
    const float* x = (const float*)d_in[0];
    float* out = (float*)d_out;
    selfattn_kernel<<<dim3(512), 512, 0, stream>>>(x, out);
}